// Round 6
// baseline (234.501 us; speedup 1.0000x reference)
//
#include <hip/hip_runtime.h>

typedef unsigned int u32;
typedef unsigned short u16;
typedef __bf16 bf16_t;
typedef float f32x4 __attribute__((ext_vector_type(4)));
typedef bf16_t bfrag __attribute__((ext_vector_type(8)));
typedef u16 u16x8 __attribute__((ext_vector_type(8)));
typedef u16 u16x4 __attribute__((ext_vector_type(4)));

// ---------- helpers ----------
__device__ inline u16 f2bf(float f) {
    union { float f; u32 u; } v; v.f = f;
    u32 r = v.u + 0x7fffu + ((v.u >> 16) & 1u);   // RNE
    return (u16)(r >> 16);
}
__device__ inline float bf2f(u16 h) {
    union { u32 u; float f; } v; v.u = ((u32)h) << 16; return v.f;
}

__device__ inline f32x4 mfma16(bfrag a, bfrag b, f32x4 c) {
    return __builtin_amdgcn_mfma_f32_16x16x32_bf16(a, b, c, 0, 0, 0);
}

__device__ inline void gload_lds16(const void* g, void* l) {
    __builtin_amdgcn_global_load_lds((const __attribute__((address_space(1))) u32*)g,
                                     (__attribute__((address_space(3))) u32*)l, 16, 0, 0);
}

__device__ inline float redmax16(float v) {
    #pragma unroll
    for (int m = 1; m < 16; m <<= 1) v = fmaxf(v, __shfl_xor(v, m));
    return v;
}
__device__ inline float redsum16(float v) {
    #pragma unroll
    for (int m = 1; m < 16; m <<= 1) v += __shfl_xor(v, m);
    return v;
}

// ---------- sizes (fixed problem) ----------
// B=128 T=256 C=384 H=6 D=64; tokens M=32768
#define NTOK 32768
#define QKV_ELEMS 12582912   // 128*6*256*64

// ---------- weight prep: tiled 64x64 transpose fp32->bf16 ----------
__global__ __launch_bounds__(256) void prep_weights(
    const float* __restrict__ Wq, const float* __restrict__ Wk,
    const float* __restrict__ Wv, const float* __restrict__ Wo,
    const float* __restrict__ W1, const float* __restrict__ W2,
    u16* __restrict__ wqkvT, u16* __restrict__ woT,
    u16* __restrict__ w1T, u16* __restrict__ w2T)
{
    __shared__ float tile[64][65];
    const int b = blockIdx.x;
    const float* src; u16* dst;
    int sr0, sc0, srs, dr0, dc0, drs;
    if (b < 36) {                       // Wo [384][384] -> woT [384][384]
        int i = b / 6, j = b - i * 6;
        src = Wo;  srs = 384;  sr0 = i * 64; sc0 = j * 64;
        dst = woT; drs = 384;  dr0 = j * 64; dc0 = i * 64;
    } else if (b < 180) {               // W1 [384][1536] -> w1T [1536][384]
        int t = b - 36; int i = t / 24, j = t - i * 24;
        src = W1;  srs = 1536; sr0 = i * 64; sc0 = j * 64;
        dst = w1T; drs = 384;  dr0 = j * 64; dc0 = i * 64;
    } else if (b < 324) {               // W2 [1536][384] -> w2T [384][1536]
        int t = b - 180; int i = t / 6, j = t - i * 6;
        src = W2;  srs = 384;  sr0 = i * 64; sc0 = j * 64;
        dst = w2T; drs = 1536; dr0 = j * 64; dc0 = i * 64;
    } else {                            // W{q,k,v} [6][384][64] -> wqkvT [1152][384]
        int t = b - 324;
        int m2 = t / 36; t -= m2 * 36;
        int h = t / 6, tt = t - h * 6;
        src = (m2 == 0) ? Wq : ((m2 == 1) ? Wk : Wv);
        srs = 64;  sr0 = h * 384 + tt * 64; sc0 = 0;
        dst = wqkvT; drs = 384; dr0 = m2 * 384 + h * 64; dc0 = tt * 64;
    }
    const int lane = threadIdx.x & 63, grp = threadIdx.x >> 6;
    #pragma unroll
    for (int i = 0; i < 16; i++) {
        int r = grp * 16 + i;
        tile[r][lane] = src[(size_t)(sr0 + r) * srs + sc0 + lane];
    }
    __syncthreads();
    #pragma unroll
    for (int i = 0; i < 16; i++) {
        int r = grp * 16 + i;
        dst[(size_t)(dr0 + r) * drs + dc0 + lane] = f2bf(tile[lane][r]);
    }
}

// ---------- layernorm fp32-in ----------
__global__ __launch_bounds__(256) void ln_f32(
    const float* __restrict__ x, const float* __restrict__ g,
    const float* __restrict__ b, u16* __restrict__ out)
{
    const int row = blockIdx.x * 4 + (threadIdx.x >> 6);
    const int lane = threadIdx.x & 63;
    const float2* xr = (const float2*)(x + (size_t)row * 384);
    float2 v[3];
    float s = 0.f, s2 = 0.f;
    #pragma unroll
    for (int i = 0; i < 3; i++) {
        v[i] = xr[lane + i * 64];
        s += v[i].x + v[i].y; s2 += v[i].x * v[i].x + v[i].y * v[i].y;
    }
    #pragma unroll
    for (int m = 1; m < 64; m <<= 1) { s += __shfl_xor(s, m); s2 += __shfl_xor(s2, m); }
    float mean = s * (1.f / 384.f);
    float rstd = rsqrtf(s2 * (1.f / 384.f) - mean * mean + 1e-5f);
    u32* op = (u32*)(out + (size_t)row * 384);
    #pragma unroll
    for (int i = 0; i < 3; i++) {
        int c = (lane + i * 64) * 2;
        u32 lo = f2bf((v[i].x - mean) * rstd * g[c] + b[c]);
        u32 hi = f2bf((v[i].y - mean) * rstd * g[c + 1] + b[c + 1]);
        op[lane + i * 64] = lo | (hi << 16);
    }
}

// ---------- layernorm bf16-in ----------
__global__ __launch_bounds__(256) void ln_bf16(
    const u16* __restrict__ x, const float* __restrict__ g,
    const float* __restrict__ b, u16* __restrict__ out)
{
    const int row = blockIdx.x * 4 + (threadIdx.x >> 6);
    const int lane = threadIdx.x & 63;
    const u32* xr = (const u32*)(x + (size_t)row * 384);
    float vx[3], vy[3];
    float s = 0.f, s2 = 0.f;
    #pragma unroll
    for (int i = 0; i < 3; i++) {
        u32 w = xr[lane + i * 64];
        vx[i] = bf2f((u16)(w & 0xffffu));
        vy[i] = bf2f((u16)(w >> 16));
        s += vx[i] + vy[i]; s2 += vx[i] * vx[i] + vy[i] * vy[i];
    }
    #pragma unroll
    for (int m = 1; m < 64; m <<= 1) { s += __shfl_xor(s, m); s2 += __shfl_xor(s2, m); }
    float mean = s * (1.f / 384.f);
    float rstd = rsqrtf(s2 * (1.f / 384.f) - mean * mean + 1e-5f);
    u32* op = (u32*)(out + (size_t)row * 384);
    #pragma unroll
    for (int i = 0; i < 3; i++) {
        int c = (lane + i * 64) * 2;
        u32 lo = f2bf((vx[i] - mean) * rstd * g[c] + b[c]);
        u32 hi = f2bf((vy[i] - mean) * rstd * g[c + 1] + b[c + 1]);
        op[lane + i * 64] = lo | (hi << 16);
    }
}

// ---------- m97-structure GEMM + wide-store LDS epilogue ----------
// A[M,K] x Bt[N,K], 128x128 tile, BK=64, 4 waves, 64x64 wave tiles, acc[4][4].
// Staging: single 32 KB buffer (smem[0..16383]), 2 barriers/step, 4 blocks/CU.
// Epilogue: acc -> padded LDS tile -> 16 B/lane coalesced global stores
// (full-cacheline coverage; avoids write-allocate HBM fetch of the output).
// EPI 0: qkv scatter (bf16, q scaled)  EPI 1: bf16 out = f32resid + bias + acc
// EPI 2: bf16 out = relu(acc + bias)   EPI 3: f32 out = bf16resid + bias + acc
template<int EPI, int NT>
__global__ __launch_bounds__(256, 4) void gemm_m97(
    const u16* __restrict__ A, const u16* __restrict__ Bt,
    const float* __restrict__ bias, const void* __restrict__ resid,
    void* __restrict__ outp, int M, int N)
{
    const int K = NT * 64;
    __shared__ __align__(16) u16 smem[17408];   // 34816 B: staging 32 KB; epilogue tile
    u16* As = smem;
    u16* Bs = smem + 8192;
    const int tid = threadIdx.x, wave = tid >> 6, lane = tid & 63;
    const int nbn = N >> 7;
    const int nwg = gridDim.x;
    const int bid = blockIdx.x;
    const int wg = (bid & 7) * (nwg >> 3) + (bid >> 3);   // XCD-chunked swizzle
    const int bm = wg / nbn, bn = wg - bm * nbn;          // bn fastest: A reuse in-XCD
    const int rowA0 = bm << 7, rowB0 = bn << 7;
    const int wm = (wave >> 1) << 6, wn = (wave & 1) << 6;
    const int lr = lane >> 3, lc = lane & 7;
    f32x4 acc[4][4] = {};

    for (int t = 0; t < NT; ++t) {
        const int ko = t << 6;
        #pragma unroll
        for (int p = 0; p < 4; p++) {
            const int idx = p * 4 + wave;
            const int r = idx * 8 + lr;
            const int csrc = ((lc ^ (r & 7)) << 3);
            gload_lds16(A + (size_t)(rowA0 + r) * K + ko + csrc, &As[idx * 512]);
            gload_lds16(Bt + (size_t)(rowB0 + r) * K + ko + csrc, &Bs[idx * 512]);
        }
        __syncthreads();
        #pragma unroll
        for (int kk = 0; kk < 2; kk++) {
            bfrag af[4], bfr[4];
            #pragma unroll
            for (int mt = 0; mt < 4; mt++) {
                const int row = wm + mt * 16 + (lane & 15);
                af[mt] = *(const bfrag*)((const char*)As + row * 128 +
                          (((kk * 4 + (lane >> 4)) ^ (row & 7)) << 4));
            }
            #pragma unroll
            for (int nt = 0; nt < 4; nt++) {
                const int row = wn + nt * 16 + (lane & 15);
                bfr[nt] = *(const bfrag*)((const char*)Bs + row * 128 +
                          (((kk * 4 + (lane >> 4)) ^ (row & 7)) << 4));
            }
            #pragma unroll
            for (int mt = 0; mt < 4; mt++)
                #pragma unroll
                for (int nt = 0; nt < 4; nt++)
                    acc[mt][nt] = mfma16(af[mt], bfr[nt], acc[mt][nt]);
        }
        __syncthreads();
    }

    // ---- epilogue ----
    if constexpr (EPI != 3) {
        // bf16 tile [128][136] (272 B rows: 16-B aligned, low bank conflict)
        #pragma unroll
        for (int mt = 0; mt < 4; mt++)
            #pragma unroll
            for (int nt = 0; nt < 4; nt++)
                #pragma unroll
                for (int r2 = 0; r2 < 4; r2++) {
                    const int lr2 = wm + mt * 16 + ((lane >> 4) << 2) + r2;
                    const int lc2 = wn + nt * 16 + (lane & 15);
                    float v = acc[mt][nt][r2];
                    if constexpr (EPI == 0) { if (rowB0 + lc2 < 384) v *= 0.125f; }
                    smem[lr2 * 136 + lc2] = f2bf(v);
                }
        __syncthreads();
        #pragma unroll
        for (int it = 0; it < 8; it++) {
            const int flat = it * 2048 + tid * 8;
            const int row = flat >> 7, col = flat & 127;
            u16x8 pk = *(const u16x8*)&smem[row * 136 + col];
            const int gr = rowA0 + row;
            const int gc0 = rowB0 + col;
            if constexpr (EPI == 0) {
                const int m2 = gc0 / 384, rem = gc0 - m2 * 384;
                const int hh = rem >> 6, d0 = rem & 63;
                const int bb = gr >> 8, tt2 = gr & 255;
                *(u16x8*)&((u16*)outp)[(size_t)m2 * QKV_ELEMS +
                    ((size_t)((bb * 6 + hh) * 256 + tt2) << 6) + d0] = pk;
            } else if constexpr (EPI == 1) {
                const float* rr = (const float*)resid + (size_t)gr * N + gc0;
                float4 ra = *(const float4*)rr;
                float4 rb = *(const float4*)(rr + 4);
                float4 ba = *(const float4*)&bias[gc0];
                float4 bb4 = *(const float4*)&bias[gc0 + 4];
                u16x8 o;
                o[0] = f2bf(bf2f(pk[0]) + ra.x + ba.x);
                o[1] = f2bf(bf2f(pk[1]) + ra.y + ba.y);
                o[2] = f2bf(bf2f(pk[2]) + ra.z + ba.z);
                o[3] = f2bf(bf2f(pk[3]) + ra.w + ba.w);
                o[4] = f2bf(bf2f(pk[4]) + rb.x + bb4.x);
                o[5] = f2bf(bf2f(pk[5]) + rb.y + bb4.y);
                o[6] = f2bf(bf2f(pk[6]) + rb.z + bb4.z);
                o[7] = f2bf(bf2f(pk[7]) + rb.w + bb4.w);
                *(u16x8*)&((u16*)outp)[(size_t)gr * N + gc0] = o;
            } else {   // EPI == 2: relu(acc + bias)
                float4 ba = *(const float4*)&bias[gc0];
                float4 bb4 = *(const float4*)&bias[gc0 + 4];
                u16x8 o;
                float t0;
                t0 = bf2f(pk[0]) + ba.x;  o[0] = f2bf(t0 > 0.f ? t0 : 0.f);
                t0 = bf2f(pk[1]) + ba.y;  o[1] = f2bf(t0 > 0.f ? t0 : 0.f);
                t0 = bf2f(pk[2]) + ba.z;  o[2] = f2bf(t0 > 0.f ? t0 : 0.f);
                t0 = bf2f(pk[3]) + ba.w;  o[3] = f2bf(t0 > 0.f ? t0 : 0.f);
                t0 = bf2f(pk[4]) + bb4.x; o[4] = f2bf(t0 > 0.f ? t0 : 0.f);
                t0 = bf2f(pk[5]) + bb4.y; o[5] = f2bf(t0 > 0.f ? t0 : 0.f);
                t0 = bf2f(pk[6]) + bb4.z; o[6] = f2bf(t0 > 0.f ? t0 : 0.f);
                t0 = bf2f(pk[7]) + bb4.w; o[7] = f2bf(t0 > 0.f ? t0 : 0.f);
                *(u16x8*)&((u16*)outp)[(size_t)gr * N + gc0] = o;
            }
        }
    } else {
        // fp32 out, two 64-row halves through LDS [64][132] f32
        float* sf = (float*)smem;
        #pragma unroll
        for (int half = 0; half < 2; half++) {
            if ((wm >> 6) == half) {
                #pragma unroll
                for (int mt = 0; mt < 4; mt++)
                    #pragma unroll
                    for (int nt = 0; nt < 4; nt++)
                        #pragma unroll
                        for (int r2 = 0; r2 < 4; r2++) {
                            const int lr2 = mt * 16 + ((lane >> 4) << 2) + r2;
                            const int lc2 = wn + nt * 16 + (lane & 15);
                            sf[lr2 * 132 + lc2] = acc[mt][nt][r2];
                        }
            }
            __syncthreads();
            #pragma unroll
            for (int it = 0; it < 8; it++) {
                const int flat4 = it * 1024 + tid * 4;
                const int row = flat4 >> 7, col = flat4 & 127;
                float4 v = *(const float4*)&sf[row * 132 + col];
                const int gr = rowA0 + half * 64 + row;
                const int gc0 = rowB0 + col;
                u16x4 rr = *(const u16x4*)&((const u16*)resid)[(size_t)gr * N + gc0];
                float4 b4 = *(const float4*)&bias[gc0];
                float4 o;
                o.x = v.x + bf2f(rr[0]) + b4.x;
                o.y = v.y + bf2f(rr[1]) + b4.y;
                o.z = v.z + bf2f(rr[2]) + b4.z;
                o.w = v.w + bf2f(rr[3]) + b4.w;
                *(float4*)&((float*)outp)[(size_t)gr * N + gc0] = o;
            }
            __syncthreads();
        }
    }
}

// ---------- attention: one block per (b,h), 8 waves ----------
__global__ __launch_bounds__(512) void attn_kernel(
    const u16* __restrict__ q, const u16* __restrict__ k, const u16* __restrict__ v,
    u16* __restrict__ outp)
{
    __shared__ __align__(16) u16 Ks[256 * 64];
    __shared__ __align__(16) u16 Vt[64 * 256];
    __shared__ __align__(16) u16 Ps[8 * 512];   // per-wave P chunk [16 q][32 key]
    const int bh = blockIdx.x;
    const int tid = threadIdx.x, wave = tid >> 6, lane = tid & 63;
    const u16* qb = q + (size_t)bh * 16384;
    const u16* kb = k + (size_t)bh * 16384;
    const u16* vb = v + (size_t)bh * 16384;

    #pragma unroll
    for (int p = 0; p < 4; p++) {
        const int idx = p * 8 + wave;
        const int r = idx * 8 + (lane >> 3);
        const int csrc = (((lane & 7) ^ (r & 7)) << 3);
        gload_lds16(kb + (size_t)r * 64 + csrc, &Ks[idx * 512]);
    }
    #pragma unroll
    for (int p = 0; p < 4; p++) {
        const int e = (p * 512 + tid) * 8;
        const int key = e >> 6, d0 = e & 63;
        u16x8 raw = *(const u16x8*)(vb + (size_t)key * 64 + d0);
        #pragma unroll
        for (int j = 0; j < 8; j++) {
            const int d = d0 + j;
            Vt[d * 256 + (((key >> 3) ^ (d & 7)) << 3) + (key & 7)] = raw[j];
        }
    }
    __syncthreads();

    const int bI = bh / 6, hh = bh - bI * 6;

    #pragma unroll
    for (int t = 0; t < 2; t++) {
        const int qtile = (t == 0) ? wave : (15 - wave);
        const int qrowbase = qtile * 16;
        bfrag qf[2];
        {
            const int r = qrowbase + (lane & 15);
            qf[0] = *(const bfrag*)(qb + (size_t)r * 64 + ((lane >> 4) << 3));
            qf[1] = *(const bfrag*)(qb + (size_t)r * 64 + 32 + ((lane >> 4) << 3));
        }
        f32x4 S[16];
        #pragma unroll
        for (int kt = 0; kt < 16; kt++) {
            if (kt <= qtile) {
                f32x4 s = {0.f, 0.f, 0.f, 0.f};
                const int key = kt * 16 + (lane & 15);
                const char* kbase = (const char*)Ks + key * 128;
                s = mfma16(qf[0], *(const bfrag*)(kbase + ((((lane >> 4)) ^ (key & 7)) << 4)), s);
                s = mfma16(qf[1], *(const bfrag*)(kbase + (((4 + (lane >> 4)) ^ (key & 7)) << 4)), s);
                if (kt == qtile) {
                    const int qit = (lane >> 4) << 2;
                    #pragma unroll
                    for (int r2 = 0; r2 < 4; r2++)
                        if ((lane & 15) > qit + r2) s[r2] = -1e30f;
                }
                S[kt] = s;
            }
        }
        float mx[4] = {-1e30f, -1e30f, -1e30f, -1e30f};
        #pragma unroll
        for (int kt = 0; kt < 16; kt++) if (kt <= qtile)
            #pragma unroll
            for (int r2 = 0; r2 < 4; r2++) mx[r2] = fmaxf(mx[r2], S[kt][r2]);
        #pragma unroll
        for (int r2 = 0; r2 < 4; r2++) mx[r2] = redmax16(mx[r2]);
        float sm[4] = {0.f, 0.f, 0.f, 0.f};
        #pragma unroll
        for (int kt = 0; kt < 16; kt++) if (kt <= qtile)
            #pragma unroll
            for (int r2 = 0; r2 < 4; r2++) {
                float p = __expf(S[kt][r2] - mx[r2]);
                S[kt][r2] = p; sm[r2] += p;
            }
        #pragma unroll
        for (int r2 = 0; r2 < 4; r2++) sm[r2] = redsum16(sm[r2]);

        f32x4 O[4] = {};
        u16* Pw = &Ps[wave * 512];
        const int nch = (qtile + 2) >> 1;
        #pragma unroll
        for (int ch = 0; ch < 8; ch++) {
            if (ch < nch) {
                #pragma unroll
                for (int ktl = 0; ktl < 2; ktl++) {
                    const int kt = ch * 2 + ktl;
                    const int keyl = ktl * 16 + (lane & 15);
                    const int cidx = keyl >> 3;
                    #pragma unroll
                    for (int r2 = 0; r2 < 4; r2++) {
                        const int qq = ((lane >> 4) << 2) + r2;
                        float pv = (kt <= qtile) ? S[kt][r2] : 0.f;
                        Pw[qq * 32 + ((cidx ^ (qq & 3)) << 3) + (keyl & 7)] = f2bf(pv);
                    }
                }
                const int qq = lane & 15;
                bfrag pa = *(const bfrag*)(Pw + qq * 32 + (((lane >> 4) ^ (qq & 3)) << 3));
                #pragma unroll
                for (int dt = 0; dt < 4; dt++) {
                    const int d = dt * 16 + (lane & 15);
                    const int cc = ch * 4 + (lane >> 4);
                    bfrag vf = *(const bfrag*)((const char*)Vt + d * 512 + ((cc ^ (d & 7)) << 4));
                    O[dt] = mfma16(pa, vf, O[dt]);
                }
            }
        }
        #pragma unroll
        for (int dt = 0; dt < 4; dt++) {
            #pragma unroll
            for (int r2 = 0; r2 < 4; r2++) {
                const int qg = qrowbase + ((lane >> 4) << 2) + r2;
                const float val = O[dt][r2] / sm[r2];
                outp[(size_t)(bI * 256 + qg) * 384 + hh * 64 + dt * 16 + (lane & 15)] = f2bf(val);
            }
        }
    }
}

// ---------- launch ----------
extern "C" void kernel_launch(void* const* d_in, const int* in_sizes, int n_in,
                              void* d_out, int out_size, void* d_ws, size_t ws_size,
                              hipStream_t stream)
{
    const float* x    = (const float*)d_in[0];
    const float* ln1g = (const float*)d_in[1];
    const float* ln1b = (const float*)d_in[2];
    const float* Wq   = (const float*)d_in[3];
    const float* Wk   = (const float*)d_in[4];
    const float* Wv   = (const float*)d_in[5];
    const float* Wo   = (const float*)d_in[6];
    const float* bo   = (const float*)d_in[7];
    const float* ln2g = (const float*)d_in[8];
    const float* ln2b = (const float*)d_in[9];
    const float* W1   = (const float*)d_in[10];
    const float* b1   = (const float*)d_in[11];
    const float* W2   = (const float*)d_in[12];
    const float* b2   = (const float*)d_in[13];

    if (ws_size < 230031360u) return;

    char* ws = (char*)d_ws;
    u16*   wqkvT = (u16*)(ws + 0);
    u16*   woT   = (u16*)(ws + 884736);
    u16*   w1T   = (u16*)(ws + 1179648);
    u16*   w2T   = (u16*)(ws + 2359296);
    u16*   hbuf  = (u16*)(ws + 3538944);    // LN1 out, later attn out
    u16*   qbuf  = (u16*)(ws + 28704768);   // q, later h2 (LN2 out)
    u16*   kbuf  = (u16*)(ws + 53870592);
    u16*   vbuf  = (u16*)(ws + 79036416);
    u16*   x2h   = (u16*)(ws + 104202240);  // bf16 residual stream
    u16*   mid   = (u16*)(ws + 129368064);  // FFN hidden (bf16)
    float* out   = (float*)d_out;

    prep_weights<<<432, 256, 0, stream>>>(Wq, Wk, Wv, Wo, W1, W2, wqkvT, woT, w1T, w2T);
    ln_f32<<<8192, 256, 0, stream>>>(x, ln1g, ln1b, hbuf);
    gemm_m97<0, 6><<<2304, 256, 0, stream>>>(hbuf, wqkvT, nullptr, nullptr, qbuf,
                                             NTOK, 1152);
    attn_kernel<<<768, 512, 0, stream>>>(qbuf, kbuf, vbuf, hbuf);
    gemm_m97<1, 6><<<768, 256, 0, stream>>>(hbuf, woT, bo, x, x2h, NTOK, 384);
    ln_bf16<<<8192, 256, 0, stream>>>(x2h, ln2g, ln2b, qbuf);
    gemm_m97<2, 6><<<3072, 256, 0, stream>>>(qbuf, w1T, b1, nullptr, mid, NTOK, 1536);
    gemm_m97<3, 24><<<768, 256, 0, stream>>>(mid, w2T, b2, x2h, out, NTOK, 384);
}